// Round 3
// baseline (141.385 us; speedup 1.0000x reference)
//
#include <hip/hip_runtime.h>

// SA_Head: B=4, S=4096, E=256, H=64
//   out = softmax((emb@wq)(emb@wk)^T / 16) (emb@wv)
// R7: attn rebuilt on native 32x32x16 MFMAs (legacy 16x16x16_1k PV measured
// ~quarter-rate: MfmaUtil 17.8% was mostly PV). Per wave: 32key x 32q S^T
// tile via 4 chained 32x32x16 (K=H=64); P->B-frag in-register via
// 8 cvt_pk + 4 v_permlane32_swap per tt; PV = 4x 32x32x16. V loads 16B
// contiguous; lacc = 1 reg; oacc = 32 regs; 2-stage b128 epilogue.
// (R6: K+V dbuf prefetch, split-K x2, XCD swizzle. R4 base: no-max softmax
//  |s|<=4, S^T-form QK keeps P in registers, V pre-transposed vbt[h][s].)

typedef short short4v __attribute__((ext_vector_type(4)));
typedef short short8v __attribute__((ext_vector_type(8)));
typedef float floatx4 __attribute__((ext_vector_type(4)));
typedef float floatx16 __attribute__((ext_vector_type(16)));
typedef unsigned short u16;
typedef unsigned int u32;

#define SEQ 4096
#define EMB 256
#define HD 64
#define PADA 264   // u16 stride for proj A tile
#define OSTR 68    // f32 stride for attn epilogue O[q][h] tile

static __device__ __forceinline__ u16 f2bf(float x) {
    union { float f; unsigned u; } v; v.f = x;
    unsigned r = v.u + 0x7FFFu + ((v.u >> 16) & 1u);
    return (u16)(r >> 16);
}

static __device__ __forceinline__ u32 cvt_pk_bf16(float a, float b) {
    u32 r;
    asm("v_cvt_pk_bf16_f32 %0, %1, %2" : "=v"(r) : "v"(a), "v"(b));
    return r;
}

// ---------------- W prep: fragment-major Wt --------------------------------------
// wt element order: ((nt*8+kc)*64 + lane)*8 + j  (u16), holding
// W[e=kc*32+(lane>>4)*8+j][col=nt*16+(lane&15)] * scale.  nt: 0..11 (q|k|v x4).
__global__ __launch_bounds__(256) void prep_w(
    const float* __restrict__ wk, const float* __restrict__ wq, const float* __restrict__ wv,
    u16* __restrict__ wt) {
    const int nt = blockIdx.x;   // 0..11
    const int t = threadIdx.x;
#pragma unroll
    for (int ss = 0; ss < 2; ++ss) {
        int slot = t + ss * 256;          // 0..511
        int kc = slot >> 6, lane = slot & 63;
        int ln15 = lane & 15, lq = lane >> 4;
        int cg = nt * 16 + ln15;
        int mat = cg >> 6, col = cg & 63;
        const float* W = (mat == 0) ? wq : (mat == 1) ? wk : wv;
        const float s = (mat == 0) ? 0.0625f * 1.44269504088896f : 1.0f;
        u32 w4[4];
#pragma unroll
        for (int p = 0; p < 2; ++p) {
#pragma unroll
            for (int d = 0; d < 2; ++d) {
                int e0 = kc * 32 + lq * 8 + p * 4 + d * 2;
                u16 lo = f2bf(W[(e0 + 0) * HD + col] * s);
                u16 hi = f2bf(W[(e0 + 1) * HD + col] * s);
                w4[p * 2 + d] = (u32)lo | ((u32)hi << 16);
            }
        }
        u32* dst = (u32*)wt + ((size_t)(nt * 8 + kc) * 64 + lane) * 4;
        *(uint4*)dst = make_uint4(w4[0], w4[1], w4[2], w4[3]);
    }
}

// ---------------- projection GEMM: [16384,256]@[256,192] bf16 MFMA ----------------
// grid 1024 x 256; 16 rows/block; wave w covers ntiles 3w..3w+2; v -> vbt[h][s].
__global__ __launch_bounds__(256) void proj_mfma(
    const float* __restrict__ emb, const u16* __restrict__ wt,
    u16* __restrict__ qb, u16* __restrict__ kb, u16* __restrict__ vbt) {
    __shared__ u16 a_s[16 * PADA];
    const int t = threadIdx.x;
    const int lane = t & 63;
    const int wave = t >> 6;
    const int ln15 = lane & 15;
    const int lq = lane >> 4;
    const size_t row0 = (size_t)blockIdx.x * 16;

    // coalesced staging: flat float4 f = t + c*256 -> row f>>6, cols (f&63)*4
#pragma unroll
    for (int c = 0; c < 4; ++c) {
        int f = t + c * 256;
        int row = f >> 6, e4 = (f & 63) * 4;
        float4 v = *(const float4*)(emb + (row0 + row) * EMB + e4);
        u32 lo = cvt_pk_bf16(v.x, v.y);
        u32 hi = cvt_pk_bf16(v.z, v.w);
        *(uint2*)&a_s[row * PADA + e4] = make_uint2(lo, hi);
    }
    __syncthreads();

    floatx4 acc[3];
#pragma unroll
    for (int j = 0; j < 3; ++j) {
        floatx4 z = { 0.f, 0.f, 0.f, 0.f };
        acc[j] = z;
    }

#pragma unroll
    for (int kc = 0; kc < 8; ++kc) {
        short8v a = *(const short8v*)&a_s[ln15 * PADA + kc * 32 + lq * 8];
#pragma unroll
        for (int j = 0; j < 3; ++j) {
            short8v b = *(const short8v*)(wt + (((size_t)(wave * 3 + j) * 8 + kc) * 64 + lane) * 8);
            acc[j] = __builtin_amdgcn_mfma_f32_16x16x32_bf16(a, b, acc[j], 0, 0, 0);
        }
    }

#pragma unroll
    for (int j = 0; j < 3; ++j) {
        int cg = (wave * 3 + j) * 16 + ln15;
        int mat = cg >> 6, col = cg & 63;
        if (mat < 2) {
            u16* O = (mat == 0) ? qb : kb;
#pragma unroll
            for (int r = 0; r < 4; ++r)
                O[(row0 + lq * 4 + r) * HD + col] = f2bf(acc[j][r]);
        } else {
            // vbt[(b*64+col)*4096 + s], s = (row0&4095)+lq*4+r : 8B contiguous
            u32 lo = cvt_pk_bf16(acc[j][0], acc[j][1]);
            u32 hi = cvt_pk_bf16(acc[j][2], acc[j][3]);
            size_t bidx = row0 >> 12;
            size_t sl = (row0 & 4095) + lq * 4;
            *(uint2*)&vbt[(bidx * 64 + col) * SEQ + sl] = make_uint2(lo, hi);
        }
    }
}

// ---------------- flash attention, split-K x2, 32x32 tiles, zero-LDS loop ---------
// part = b*128 + qt*2 + split; 4 waves; wave = kh*2+qh: keys [kw+32kh,+32),
// q [q0+32qh,+32).  S^T[key][q] = K.Q^T via 4x mfma_32x32x16 over H=64;
// P = exp2(S^T); B-frag for PV built in-register (cvt_pk + permlane32_swap);
// O^T[h][q] += V^T.P via 2 ht x 2 kstep mfma_32x32x16.  K,V double-buffered.

template <bool PF>
static __device__ __forceinline__ void attn_step(
    const int tt, const int split, const int kh, const int ln31, const int hi8,
    const u16* __restrict__ kpb, const u16* __restrict__ vpb,
    const short8v (&qf)[4],
    const short8v (&kfc)[4], const short8v (&vfc)[2][2],
    short8v (&kfn)[4], short8v (&vfn)[2][2],
    floatx16 (&oacc)[2], float& lacc) {
    const int kw = (split * 32 + tt) * 64 + kh * 32;

    // prefetch NEXT tt's K and V frags into the other buffer
    if (PF) {
        const int kwn = kw + 64;
#pragma unroll
        for (int ch = 0; ch < 4; ++ch)
            kfn[ch] = *(const short8v*)(kpb + (size_t)(kwn + ln31) * HD + ch * 16 + hi8);
#pragma unroll
        for (int ht = 0; ht < 2; ++ht)
#pragma unroll
            for (int ks = 0; ks < 2; ++ks)
                vfn[ht][ks] = *(const short8v*)(vpb + (size_t)(ht * 32 + ln31) * SEQ + kwn + ks * 16 + hi8);
    }

    // S^T tile: C[m=key][n=q]: col=ln31=q, row=(r&3)+8*(r>>2)+4*(lane>>5)=key
    floatx16 c = { 0.f, 0.f, 0.f, 0.f, 0.f, 0.f, 0.f, 0.f,
                   0.f, 0.f, 0.f, 0.f, 0.f, 0.f, 0.f, 0.f };
    __builtin_amdgcn_s_setprio(1);
#pragma unroll
    for (int ch = 0; ch < 4; ++ch)
        c = __builtin_amdgcn_mfma_f32_32x32x16_bf16(kfc[ch], qf[ch], c, 0, 0, 0);
    __builtin_amdgcn_s_setprio(0);

    // P = exp2(S^T), denominator (lane's column q gets all 16 of its keys here)
    float p[16];
#pragma unroll
    for (int r = 0; r < 16; ++r)
        p[r] = __builtin_amdgcn_exp2f(c[r]);
    lacc += ((((p[0] + p[1]) + (p[2] + p[3])) + ((p[4] + p[5]) + (p[6] + p[7])))
          + (((p[8] + p[9]) + (p[10] + p[11])) + ((p[12] + p[13]) + (p[14] + p[15]))));

    // Per 16-key step: assemble B-frag B[k=hi*8+j][q] from C-layout regs.
    // hi=0 regs hold keys {0-3,8-11}(+ks*16), hi=1 keys {4-7,12-15}:
    // swap(a0,a2) -> words 0,2; swap(a1,a3) -> words 1,3.
#pragma unroll
    for (int ks = 0; ks < 2; ++ks) {
        u32 a0 = cvt_pk_bf16(p[ks * 8 + 0], p[ks * 8 + 1]);
        u32 a1 = cvt_pk_bf16(p[ks * 8 + 2], p[ks * 8 + 3]);
        u32 a2 = cvt_pk_bf16(p[ks * 8 + 4], p[ks * 8 + 5]);
        u32 a3 = cvt_pk_bf16(p[ks * 8 + 6], p[ks * 8 + 7]);
        asm("v_permlane32_swap_b32 %0, %1" : "+v"(a0), "+v"(a2));
        asm("v_permlane32_swap_b32 %0, %1" : "+v"(a1), "+v"(a3));
        union { u32 w[4]; short8v s; } pb;
        pb.w[0] = a0; pb.w[1] = a1; pb.w[2] = a2; pb.w[3] = a3;
        __builtin_amdgcn_s_setprio(1);
#pragma unroll
        for (int ht = 0; ht < 2; ++ht)
            oacc[ht] = __builtin_amdgcn_mfma_f32_32x32x16_bf16(vfc[ht][ks], pb.s, oacc[ht], 0, 0, 0);
        __builtin_amdgcn_s_setprio(0);
    }
}

__global__ __launch_bounds__(256) void attn_kernel(
    const u16* __restrict__ qb, const u16* __restrict__ kb, const u16* __restrict__ vbt,
    float* __restrict__ po, float* __restrict__ pml) {
    __shared__ float ored[64 * OSTR];   // O[q][h], stride OSTR
    __shared__ float lred[128];

    const int t = threadIdx.x;
    const int lane = t & 63;
    const int wave = t >> 6;
    const int ln31 = lane & 31;
    const int hi8 = (lane >> 5) * 8;
    const int kh = wave >> 1;           // key half
    const int qh = wave & 1;            // q half

    // XCD-aware swizzle (512 blocks, 512%8==0 -> bijective)
    const int part = ((blockIdx.x & 7) << 6) | (blockIdx.x >> 3);
    const int b = part >> 7;
    const int qt = (part >> 1) & 63;
    const int split = part & 1;
    const int q0 = qt * 64;

    const u16* __restrict__ qpb = qb + ((size_t)b * SEQ + q0 + qh * 32) * HD;
    const u16* __restrict__ kpb = kb + (size_t)b * SEQ * HD;
    const u16* __restrict__ vpb = vbt + (size_t)b * HD * SEQ;

    // Q B-frags (loop-invariant): B[k=e][n=q] -> Q[q=ln31][e=ch*16+hi8+j]
    short8v qf[4];
#pragma unroll
    for (int ch = 0; ch < 4; ++ch)
        qf[ch] = *(const short8v*)(qpb + (size_t)ln31 * HD + ch * 16 + hi8);

    floatx16 oacc[2];
#pragma unroll
    for (int ht = 0; ht < 2; ++ht) {
        floatx16 z = { 0.f, 0.f, 0.f, 0.f, 0.f, 0.f, 0.f, 0.f,
                       0.f, 0.f, 0.f, 0.f, 0.f, 0.f, 0.f, 0.f };
        oacc[ht] = z;
    }
    float lacc = 0.f;

    // prologue: K and V frags for tt=0
    short8v kfA[4], kfB[4], vfA[2][2], vfB[2][2];
    {
        const int kw0 = (split * 32) * 64 + kh * 32;
#pragma unroll
        for (int ch = 0; ch < 4; ++ch)
            kfA[ch] = *(const short8v*)(kpb + (size_t)(kw0 + ln31) * HD + ch * 16 + hi8);
#pragma unroll
        for (int ht = 0; ht < 2; ++ht)
#pragma unroll
            for (int ks = 0; ks < 2; ++ks)
                vfA[ht][ks] = *(const short8v*)(vpb + (size_t)(ht * 32 + ln31) * SEQ + kw0 + ks * 16 + hi8);
    }

    // 32 tt steps, 2 per iteration, static buffer alternation; final PF=false.
#pragma unroll 1
    for (int tth = 0; tth < 15; ++tth) {
        attn_step<true>(2 * tth,     split, kh, ln31, hi8, kpb, vpb, qf,
                        kfA, vfA, kfB, vfB, oacc, lacc);
        attn_step<true>(2 * tth + 1, split, kh, ln31, hi8, kpb, vpb, qf,
                        kfB, vfB, kfA, vfA, oacc, lacc);
    }
    attn_step<true >(30, split, kh, ln31, hi8, kpb, vpb, qf,
                     kfA, vfA, kfB, vfB, oacc, lacc);
    attn_step<false>(31, split, kh, ln31, hi8, kpb, vpb, qf,
                     kfB, vfB, kfA, vfA, oacc, lacc);

    // ---- epilogue ----
    // denominator: lane's column q summed over the wave's 32 keys
    lacc += __shfl_xor(lacc, 32);
    if (lane < 32) lred[wave * 32 + ln31] = lacc;

    // O[q][h]: oacc[ht] reg r -> h = ht*32 + (r&3)+8*(r>>2)+4*(lane>>5), q = qh*32+ln31
    // regs g*4..g*4+3 are h-consecutive -> b128 LDS ops.  2 stages: kh=0 write, kh=1 add.
    if (kh == 0) {
#pragma unroll
        for (int ht = 0; ht < 2; ++ht)
#pragma unroll
            for (int g = 0; g < 4; ++g) {
                int h = ht * 32 + g * 8 + (hi8 >> 1);
                int idx = (qh * 32 + ln31) * OSTR + h;
                floatx4 v4 = { oacc[ht][g * 4 + 0], oacc[ht][g * 4 + 1],
                               oacc[ht][g * 4 + 2], oacc[ht][g * 4 + 3] };
                *(floatx4*)&ored[idx] = v4;
            }
    }
    __syncthreads();
    if (kh == 1) {
#pragma unroll
        for (int ht = 0; ht < 2; ++ht)
#pragma unroll
            for (int g = 0; g < 4; ++g) {
                int h = ht * 32 + g * 8 + (hi8 >> 1);
                int idx = (qh * 32 + ln31) * OSTR + h;
                floatx4 old = *(floatx4*)&ored[idx];
                floatx4 v4 = { oacc[ht][g * 4 + 0], oacc[ht][g * 4 + 1],
                               oacc[ht][g * 4 + 2], oacc[ht][g * 4 + 3] };
                old += v4;
                *(floatx4*)&ored[idx] = old;
            }
    }
    __syncthreads();

    // write po[part][q][h] (coalesced float4) and combined l
    float* __restrict__ pob = po + (size_t)part * 4096;
#pragma unroll
    for (int i = 0; i < 4; ++i) {
        int f4 = t + i * 256;             // 0..1023
        int q = f4 >> 4, h4 = (f4 & 15) * 4;
        *(float4*)&pob[q * HD + h4] = *(float4*)&ored[q * OSTR + h4];
    }
    if (t < 64)
        pml[part * 64 + t] = lred[t] + lred[64 + t];
}

// ---------------- split reduction: sum 2 splits, normalize (pure f4 stream) -------
__global__ __launch_bounds__(256) void reduce_kernel(
    const float* __restrict__ po, const float* __restrict__ pml,
    float* __restrict__ out) {
    __shared__ float ls[64];
    const int t = threadIdx.x;
    const int part0 = blockIdx.x * 2;
    const int bq = blockIdx.x;           // b = bq>>6, qt = bq&63

    if (t < 64)
        ls[t] = pml[(part0 + 0) * 64 + t] + pml[(part0 + 1) * 64 + t];
    __syncthreads();

    const float* __restrict__ p0 = po + (size_t)(part0 + 0) * 4096;
    const float* __restrict__ p1 = po + (size_t)(part0 + 1) * 4096;
    float* __restrict__ ob = out + (((size_t)(bq >> 6) * SEQ + (size_t)(bq & 63) * 64)) * HD;

#pragma unroll
    for (int i = 0; i < 4; ++i) {
        int f4 = t + i * 256;            // 0..1023
        int f = f4 * 4;
        int q = f4 >> 4;
        float4 a = *(const float4*)&p0[f];
        float4 c = *(const float4*)&p1[f];
        float inv = 1.0f / ls[q];
        float4 r;
        r.x = (a.x + c.x) * inv;
        r.y = (a.y + c.y) * inv;
        r.z = (a.z + c.z) * inv;
        r.w = (a.w + c.w) * inv;
        *(float4*)&ob[f] = r;
    }
}

extern "C" void kernel_launch(void* const* d_in, const int* in_sizes, int n_in,
                              void* d_out, int out_size, void* d_ws, size_t ws_size,
                              hipStream_t stream) {
    const float* emb = (const float*)d_in[0];
    const float* wk  = (const float*)d_in[1];
    const float* wq  = (const float*)d_in[2];
    const float* wv  = (const float*)d_in[3];

    // ws: qb 2M @0, kb 2M @2M, vbt 2M @4M, wt 96K @6M, po 8M @6.25M, pml 128K @22.25M
    u16* qb  = (u16*)d_ws;
    u16* kb  = (u16*)((char*)d_ws + (size_t)2 * 1024 * 1024);
    u16* vbt = (u16*)((char*)d_ws + (size_t)4 * 1024 * 1024);
    u16* wt  = (u16*)((char*)d_ws + (size_t)6 * 1024 * 1024);
    float* po  = (float*)((char*)d_ws + (size_t)6 * 1024 * 1024 + 256 * 1024);
    float* pml = (float*)((char*)d_ws + (size_t)22 * 1024 * 1024 + 256 * 1024);
    float* out = (float*)d_out;

    prep_w<<<12, 256, 0, stream>>>(wk, wq, wv, wt);
    proj_mfma<<<1024, 256, 0, stream>>>(emb, wt, qb, kb, vbt);
    attn_kernel<<<512, 256, 0, stream>>>(qb, kb, vbt, po, pml);
    reduce_kernel<<<256, 256, 0, stream>>>(po, pml, out);
}